// Round 1
// baseline (121.110 us; speedup 1.0000x reference)
//
#include <hip/hip_runtime.h>
#include <math.h>

#define BB 16
#define LL 100
#define NCLS 80

// level constants
__device__ __constant__ int   d_W[3]     = {80, 40, 20};
__device__ __constant__ int   d_HW[3]    = {6400, 1600, 400};
__device__ __constant__ float d_stride[3]= {8.f, 16.f, 32.f};
__device__ __constant__ int   d_gtoff[3] = {0, 307200, 384000};
__device__ __constant__ float d_anch[3][3][2] = {
  {{10.f,13.f},{16.f,30.f},{33.f,23.f}},
  {{30.f,61.f},{62.f,45.f},{59.f,119.f}},
  {{116.f,90.f},{156.f,198.f},{373.f,326.f}}};

// workspace layout (in floats)
#define GTOBJ_FLOATS 403200
#define ACC_OFF      403200   // 12 floats: box[3], cls[3], cnt[3], obj[3]
#define NL_OFF       403212   // 16 ints
#define WS_FLOATS    (403212 + 16)

__device__ __forceinline__ float softplusf(float t) {
  return fmaxf(t, 0.f) + log1pf(expf(-fabsf(t)));
}
__device__ __forceinline__ float sigmoidf_(float x) {
  return 1.f / (1.f + expf(-x));
}

__device__ __forceinline__ float ciou_(float px, float py, float pw, float ph,
                                       float gx, float gy, float gw, float gh) {
  const float eps = 1e-9f;
  float b1x1 = px - pw*0.5f, b1x2 = px + pw*0.5f;
  float b1y1 = py - ph*0.5f, b1y2 = py + ph*0.5f;
  float b2x1 = gx - gw*0.5f, b2x2 = gx + gw*0.5f;
  float b2y1 = gy - gh*0.5f, b2y2 = gy + gh*0.5f;
  float iw = fmaxf(fminf(b1x2,b2x2) - fmaxf(b1x1,b2x1), 0.f);
  float ih = fmaxf(fminf(b1y2,b2y2) - fmaxf(b1y1,b2y1), 0.f);
  float inter = iw*ih;
  float w1 = b1x2-b1x1, h1 = b1y2-b1y1 + eps;
  float w2 = b2x2-b2x1, h2 = b2y2-b2y1 + eps;
  float uni = w1*h1 + w2*h2 - inter + eps;
  float iou = inter/uni;
  float cw = fmaxf(b1x2,b2x2) - fminf(b1x1,b2x1);
  float ch = fmaxf(b1y2,b2y2) - fminf(b1y1,b2y1);
  float c2 = cw*cw + ch*ch + eps;
  float dx = b2x1+b2x2-b1x1-b1x2;
  float dy = b2y1+b2y2-b1y1-b1y2;
  float rho2 = (dx*dx + dy*dy)*0.25f;
  float at = atanf(w2/h2) - atanf(w1/h1);
  float v = (float)(4.0/(M_PI*M_PI)) * at*at;
  float alpha = v / (1.0f + eps - iou + v);
  return iou - (rho2/c2 + v*alpha);
}

__global__ void k_nlabel(const float* __restrict__ yt, int* __restrict__ nlabel) {
  int t = blockIdx.x*blockDim.x + threadIdx.x;
  if (t >= BB*LL) return;
  int b = t / LL;
  const float* row = yt + t*5;
  float s = row[0]+row[1]+row[2]+row[3]+row[4];
  if (s > 0.f) atomicAdd(&nlabel[b], 1);
}

__global__ __launch_bounds__(64)
void k_match(const float* __restrict__ p0, const float* __restrict__ p1,
             const float* __restrict__ p2, const float* __restrict__ yt,
             const int* __restrict__ nlabel,
             unsigned int* __restrict__ gtobj, float* __restrict__ acc)
{
  int tid = blockIdx.x*64 + threadIdx.x;     // 72000 total, 24000/level (64 | 24000)
  int lvl = tid / 24000;
  int rem = tid - lvl*24000;
  int g   = rem / 15;
  int ao  = rem - g*15;
  int a   = ao / 5;
  int o   = ao - a*5;
  int b   = g / LL;
  int l   = g - b*LL;

  float box_c = 0.f, cls_c = 0.f, cnt_c = 0.f;

  float s  = d_stride[lvl];
  int   W  = d_W[lvl];
  int   HW = d_HW[lvl];
  const float* pr = (lvl==0) ? p0 : (lvl==1) ? p1 : p2;

  const float* row = yt + g*5;
  float tx = row[0], ty = row[1], tw = row[2], th = row[3];
  int label = (int)row[4];
  float cx = (tx + tw*0.5f)/s;
  float cy = (ty + th*0.5f)/s;
  float w  = tw/s, h = th/s;
  float aw = d_anch[lvl][a][0]/s;
  float ah = d_anch[lvl][a][1]/s;
  float rw = w/aw, rh = h/ah;
  float maxr = fmaxf(fmaxf(rw, 1.f/rw), fmaxf(rh, 1.f/rh));
  bool act = (l < nlabel[b]) && (maxr < 4.0f);
  float fx = cx - floorf(cx), fy = cy - floorf(cy);
  bool c;
  switch (o) {
    case 0: c = true; break;
    case 1: c = (cx > 1.f) && (fx < 0.5f); break;
    case 2: c = (cy > 1.f) && (fy < 0.5f); break;
    case 3: c = (cx < (float)(W-1)) && (fx > 0.5f); break;
    default:c = (cy < (float)(W-1)) && (fy > 0.5f); break;  // H == W here
  }
  act = act && c;

  if (act) {
    const float offx[5] = {0.f,-0.5f,0.f,0.5f,0.f};
    const float offy[5] = {0.f,0.f,-0.5f,0.f,0.5f};
    int gx = (int)(cx + offx[o]);
    int gy = (int)(cy + offy[o]);
    const float* base = pr + ((b*255 + a*85)*HW + gy*W + gx);
    float x0 = base[0];
    float x1 = base[1*HW];
    float x2 = base[2*HW];
    float x3 = base[3*HW];
    float pxc = sigmoidf_(x0) + (float)gx;
    float pyc = sigmoidf_(x1) + (float)gy;
    float pw = expf(x2)*aw, ph = expf(x3)*ah;
    float ci = ciou_(pxc,pyc,pw,ph, cx,cy,w,h);
    box_c = 1.f - ci;
    cnt_c = 1.f;
    float objv = fmaxf(ci, 0.f);   // CIOU_RATIO == 1
    atomicMax(&gtobj[d_gtoff[lvl] + (b*3 + a)*HW + gy*W + gx], __float_as_uint(objv));
    float cs = 0.f;
    #pragma unroll 4
    for (int cc = 0; cc < NCLS; ++cc) {
      float x = base[(5+cc)*HW];
      cs += (cc == label) ? softplusf(-x) : softplusf(x);
    }
    cls_c = cs;
  }

  // block == one wave; every wave is level-uniform (24000 % 64 == 0)
  for (int off = 32; off; off >>= 1) {
    box_c += __shfl_down(box_c, off);
    cls_c += __shfl_down(cls_c, off);
    cnt_c += __shfl_down(cnt_c, off);
  }
  if (threadIdx.x == 0) {
    atomicAdd(&acc[lvl],     box_c);
    atomicAdd(&acc[3 + lvl], cls_c);
    atomicAdd(&acc[6 + lvl], cnt_c);
  }
}

__global__ __launch_bounds__(256)
void k_obj(const float* __restrict__ p0, const float* __restrict__ p1,
           const float* __restrict__ p2, const unsigned int* __restrict__ gtobj,
           float* __restrict__ acc)
{
  int tid = blockIdx.x*256 + threadIdx.x;    // 403200 total; 256 | every level size
  int lvl, idx, HW; const float* pr;
  if (tid < 307200)      { lvl=0; idx=tid;         HW=6400; pr=p0; }
  else if (tid < 384000) { lvl=1; idx=tid-307200;  HW=1600; pr=p1; }
  else                   { lvl=2; idx=tid-384000;  HW=400;  pr=p2; }
  int b = idx/(3*HW); int r2 = idx - b*3*HW; int a = r2/HW; int pos = r2 - a*HW;
  float x = pr[(b*255 + a*85 + 4)*HW + pos];
  float z = __uint_as_float(gtobj[tid]);     // levels concatenated -> index == tid
  float v = z*softplusf(-x) + (1.f - z)*softplusf(x);

  for (int off = 32; off; off >>= 1) v += __shfl_down(v, off);
  __shared__ float sh[4];
  if ((threadIdx.x & 63) == 0) sh[threadIdx.x >> 6] = v;
  __syncthreads();
  if (threadIdx.x == 0)
    atomicAdd(&acc[9 + lvl], sh[0]+sh[1]+sh[2]+sh[3]);
}

__global__ void k_fin(const float* __restrict__ acc, float* __restrict__ out) {
  float lb = 0.f, lc = 0.f, lo = 0.f;
  const float cnts[3] = {307200.f, 76800.f, 19200.f};
  for (int l = 0; l < 3; ++l) {
    float nval  = acc[6 + l];
    float denom = fmaxf(nval, 1.f);
    if (nval > 0.f) {
      lb += acc[l] / denom;
      lc += acc[3 + l] / (denom * (float)NCLS);
    }
    lo += acc[9 + l] / cnts[l];
  }
  lb *= 0.05f;
  lc *= 0.58f;   // lo *= 1.0
  out[0] = lb + lo + lc;
  out[1] = lb;
  out[2] = lo;
  out[3] = lc;
}

extern "C" void kernel_launch(void* const* d_in, const int* in_sizes, int n_in,
                              void* d_out, int out_size, void* d_ws, size_t ws_size,
                              hipStream_t stream) {
  const float* p0 = (const float*)d_in[0];
  const float* p1 = (const float*)d_in[1];
  const float* p2 = (const float*)d_in[2];
  const float* yt = (const float*)d_in[3];

  float*        wsf   = (float*)d_ws;
  unsigned int* gtobj = (unsigned int*)d_ws;
  float*        acc   = wsf + ACC_OFF;
  int*          nlab  = (int*)(wsf + NL_OFF);

  hipMemsetAsync(d_ws, 0, WS_FLOATS * sizeof(float), stream);
  k_nlabel<<<(BB*LL + 255)/256, 256, 0, stream>>>(yt, nlab);
  k_match<<<72000/64, 64, 0, stream>>>(p0, p1, p2, yt, nlab, gtobj, acc);
  k_obj<<<403200/256, 256, 0, stream>>>(p0, p1, p2, gtobj, acc);
  k_fin<<<1, 1, 0, stream>>>(acc, (float*)d_out);
}

// Round 2
// 71.618 us; speedup vs baseline: 1.6911x; 1.6911x over previous
//
#include <hip/hip_runtime.h>
#include <math.h>

#define BB 16
#define LL 100
#define NCLS 80

// level constants
__device__ __constant__ int   d_W[3]     = {80, 40, 20};
__device__ __constant__ int   d_HW[3]    = {6400, 1600, 400};
__device__ __constant__ float d_stride[3]= {8.f, 16.f, 32.f};
__device__ __constant__ int   d_gtoff[3] = {0, 307200, 384000};
__device__ __constant__ float d_anch[3][3][2] = {
  {{10.f,13.f},{16.f,30.f},{33.f,23.f}},
  {{30.f,61.f},{62.f,45.f},{59.f,119.f}},
  {{116.f,90.f},{156.f,198.f},{373.f,326.f}}};

// workspace layout (4-byte units)
// [0,403200)        gtobj (uint, float bits)
// [403200,403212)   acc: box[3], cls[3], cnt[3], obj[3]
// 403212            ncand (uint)
// [403216,475216)   cand list (uint, capacity 72000)
#define ACC_OFF   403200
#define NCAND_OFF 403212
#define CAND_OFF  403216
#define ZERO_UNITS 403216

__device__ __forceinline__ float softplusf(float t) {
  return fmaxf(t, 0.f) + log1pf(expf(-fabsf(t)));
}
__device__ __forceinline__ float sigmoidf_(float x) {
  return 1.f / (1.f + expf(-x));
}

__device__ __forceinline__ float ciou_(float px, float py, float pw, float ph,
                                       float gx, float gy, float gw, float gh) {
  const float eps = 1e-9f;
  float b1x1 = px - pw*0.5f, b1x2 = px + pw*0.5f;
  float b1y1 = py - ph*0.5f, b1y2 = py + ph*0.5f;
  float b2x1 = gx - gw*0.5f, b2x2 = gx + gw*0.5f;
  float b2y1 = gy - gh*0.5f, b2y2 = gy + gh*0.5f;
  float iw = fmaxf(fminf(b1x2,b2x2) - fmaxf(b1x1,b2x1), 0.f);
  float ih = fmaxf(fminf(b1y2,b2y2) - fmaxf(b1y1,b2y1), 0.f);
  float inter = iw*ih;
  float w1 = b1x2-b1x1, h1 = b1y2-b1y1 + eps;
  float w2 = b2x2-b2x1, h2 = b2y2-b2y1 + eps;
  float uni = w1*h1 + w2*h2 - inter + eps;
  float iou = inter/uni;
  float cw = fmaxf(b1x2,b2x2) - fminf(b1x1,b2x1);
  float ch = fmaxf(b1y2,b2y2) - fminf(b1y1,b2y1);
  float c2 = cw*cw + ch*ch + eps;
  float dx = b2x1+b2x2-b1x1-b1x2;
  float dy = b2y1+b2y2-b1y1-b1y2;
  float rho2 = (dx*dx + dy*dy)*0.25f;
  float at = atanf(w2/h2) - atanf(w1/h1);
  float v = (float)(4.0/(M_PI*M_PI)) * at*at;
  float alpha = v / (1.0f + eps - iou + v);
  return iou - (rho2/c2 + v*alpha);
}

// one block per batch element: count nlabel in LDS, then emit packed candidates
__global__ __launch_bounds__(256)
void k_compact(const float* __restrict__ yt, unsigned int* __restrict__ cand,
               unsigned int* __restrict__ ncand)
{
  int b = blockIdx.x;
  __shared__ int s_nl;
  if (threadIdx.x == 0) s_nl = 0;
  __syncthreads();
  if (threadIdx.x < LL) {
    const float* row = yt + (size_t)(b*LL + threadIdx.x)*5;
    float sm = row[0]+row[1]+row[2]+row[3]+row[4];
    if (sm > 0.f) atomicAdd(&s_nl, 1);
  }
  __syncthreads();
  int nl = s_nl;

  const int TOT = LL*45;   // 4500 combos per batch
  for (int it = 0; it < (TOT + 255)/256; ++it) {
    int t = it*256 + threadIdx.x;
    bool act = false; unsigned int pk = 0;
    if (t < TOT) {
      int g_loc = t/45, rem = t - g_loc*45;
      int lvl = rem/15, ao = rem - lvl*15, a = ao/5, o = ao - a*5;
      const float* row = yt + (size_t)(b*LL + g_loc)*5;
      float s = d_stride[lvl];
      int W = d_W[lvl];
      float cx = (row[0] + row[2]*0.5f)/s;
      float cy = (row[1] + row[3]*0.5f)/s;
      float w = row[2]/s, h = row[3]/s;
      float aw = d_anch[lvl][a][0]/s, ah = d_anch[lvl][a][1]/s;
      float rw = w/aw, rh = h/ah;
      float maxr = fmaxf(fmaxf(rw,1.f/rw), fmaxf(rh,1.f/rh));
      bool m = (g_loc < nl) && (maxr < 4.0f);
      float fx = cx - floorf(cx), fy = cy - floorf(cy);
      bool c;
      switch (o) {
        case 0: c = true; break;
        case 1: c = (cx > 1.f) && (fx < 0.5f); break;
        case 2: c = (cy > 1.f) && (fy < 0.5f); break;
        case 3: c = (cx < (float)(W-1)) && (fx > 0.5f); break;
        default:c = (cy < (float)(W-1)) && (fy > 0.5f); break;  // H == W
      }
      if (m && c) {
        const float offx[5] = {0.f,-0.5f,0.f,0.5f,0.f};
        const float offy[5] = {0.f,0.f,-0.5f,0.f,0.5f};
        int gx = (int)(cx + offx[o]);
        int gy = (int)(cy + offy[o]);
        int g = b*LL + g_loc;
        pk = ((unsigned)lvl<<27) | ((unsigned)a<<25) | ((unsigned)g<<14)
           | ((unsigned)gy<<7) | (unsigned)gx;
        act = true;
      }
    }
    unsigned long long mball = __ballot(act);
    int cnt = __popcll(mball);
    if (cnt) {
      int lane = threadIdx.x & 63;
      int leader = __ffsll((unsigned long long)mball) - 1;
      int base = 0;
      if (lane == leader) base = (int)atomicAdd(ncand, (unsigned)cnt);
      base = __shfl(base, leader);
      if (act) {
        int pre = __popcll(mball & ((1ULL<<lane)-1ULL));
        cand[base + pre] = pk;
      }
    }
  }
}

// one wave per candidate: lanes spread the 85-channel gather
__global__ __launch_bounds__(512)
void k_gather(const float* __restrict__ p0, const float* __restrict__ p1,
              const float* __restrict__ p2, const float* __restrict__ yt,
              const unsigned int* __restrict__ cand,
              const unsigned int* __restrict__ ncand,
              unsigned int* __restrict__ gtobj, float* __restrict__ acc)
{
  __shared__ float ls[9];
  if (threadIdx.x < 9) ls[threadIdx.x] = 0.f;
  __syncthreads();
  int lane = threadIdx.x & 63;
  int wv = (blockIdx.x*512 + threadIdx.x) >> 6;
  int nw = gridDim.x * 8;
  int nc = (int)*ncand;
  float a0=0,a1=0,a2=0, c0=0,c1=0,c2=0, n0=0,n1=0,n2=0;

  for (int idx = wv; idx < nc; idx += nw) {
    unsigned pk = cand[idx];
    int gx  = pk & 127;
    int gy  = (pk>>7) & 127;
    int g   = (pk>>14) & 2047;
    int a   = (pk>>25) & 3;
    int lvl = (pk>>27) & 3;
    int b = g / LL;
    float s = d_stride[lvl];
    int W = d_W[lvl], HW = d_HW[lvl];
    const float* pr = (lvl==0) ? p0 : (lvl==1) ? p1 : p2;
    const float* row = yt + (size_t)g*5;
    float cx = (row[0] + row[2]*0.5f)/s;
    float cy = (row[1] + row[3]*0.5f)/s;
    float w  = row[2]/s, h = row[3]/s;
    int label = (int)row[4];
    float aw = d_anch[lvl][a][0]/s, ah = d_anch[lvl][a][1]/s;

    const float* base = pr + (size_t)((b*255 + a*85)*HW + gy*W + gx);
    float xA = base[(size_t)lane*HW];
    float xB = (lane < 21) ? base[(size_t)(64+lane)*HW] : 0.f;
    float x0 = __shfl(xA,0), x1 = __shfl(xA,1), x2 = __shfl(xA,2), x3 = __shfl(xA,3);

    float pxc = sigmoidf_(x0) + (float)gx;
    float pyc = sigmoidf_(x1) + (float)gy;
    float pw = expf(x2)*aw, ph = expf(x3)*ah;
    float ci = ciou_(pxc,pyc,pw,ph, cx,cy,w,h);

    float cls = 0.f;
    if (lane >= 5) { int cc = lane-5;  cls += (cc==label) ? softplusf(-xA) : softplusf(xA); }
    if (lane < 21) { int cc = 59+lane; cls += (cc==label) ? softplusf(-xB) : softplusf(xB); }
    for (int off = 1; off < 64; off <<= 1) cls += __shfl_xor(cls, off);

    if (lane == 0) {
      atomicMax(&gtobj[d_gtoff[lvl] + (b*3 + a)*HW + gy*W + gx],
                __float_as_uint(fmaxf(ci, 0.f)));
    }
    float bx = 1.f - ci;
    if      (lvl == 0) { a0 += bx; c0 += cls; n0 += 1.f; }
    else if (lvl == 1) { a1 += bx; c1 += cls; n1 += 1.f; }
    else               { a2 += bx; c2 += cls; n2 += 1.f; }
  }

  if (lane == 0) {
    if (n0 != 0.f) { atomicAdd(&ls[0],a0); atomicAdd(&ls[3],c0); atomicAdd(&ls[6],n0); }
    if (n1 != 0.f) { atomicAdd(&ls[1],a1); atomicAdd(&ls[4],c1); atomicAdd(&ls[7],n1); }
    if (n2 != 0.f) { atomicAdd(&ls[2],a2); atomicAdd(&ls[5],c2); atomicAdd(&ls[8],n2); }
  }
  __syncthreads();
  if (threadIdx.x < 9 && ls[threadIdx.x] != 0.f)
    atomicAdd(&acc[threadIdx.x], ls[threadIdx.x]);
}

// obj BCE over all cells, float4-vectorized; blocks are level-uniform (1024 | bounds)
__global__ __launch_bounds__(256)
void k_obj(const float* __restrict__ p0, const float* __restrict__ p1,
           const float* __restrict__ p2, const unsigned int* __restrict__ gtobj,
           float* __restrict__ acc)
{
  int blk = blockIdx.x;
  int lvl = (blk < 300) ? 0 : (blk < 375 ? 1 : 2);
  int e0 = blk*1024 + threadIdx.x*4;
  float v = 0.f;
  if (e0 < 403200) {
    int HW = d_HW[lvl];
    int idx = e0 - d_gtoff[lvl];
    int b = idx/(3*HW); int r2 = idx - b*3*HW; int a = r2/HW; int pos = r2 - a*HW;
    const float* pr = (lvl==0) ? p0 : (lvl==1) ? p1 : p2;
    const float4 x4 = *(const float4*)(pr + (size_t)((b*255 + a*85 + 4)*HW + pos));
    const uint4  z4 = *(const uint4*)(gtobj + e0);
    float xs[4] = {x4.x, x4.y, x4.z, x4.w};
    unsigned zs[4] = {z4.x, z4.y, z4.z, z4.w};
    #pragma unroll
    for (int i = 0; i < 4; ++i) {
      float x = xs[i];
      float z = __uint_as_float(zs[i]);
      v += z*softplusf(-x) + (1.f - z)*softplusf(x);
    }
  }
  for (int off = 32; off; off >>= 1) v += __shfl_down(v, off);
  __shared__ float sh[4];
  if ((threadIdx.x & 63) == 0) sh[threadIdx.x >> 6] = v;
  __syncthreads();
  if (threadIdx.x == 0) atomicAdd(&acc[9 + lvl], sh[0]+sh[1]+sh[2]+sh[3]);
}

__global__ void k_fin(const float* __restrict__ acc, float* __restrict__ out) {
  float lb = 0.f, lc = 0.f, lo = 0.f;
  const float cnts[3] = {307200.f, 76800.f, 19200.f};
  for (int l = 0; l < 3; ++l) {
    float nval  = acc[6 + l];
    float denom = fmaxf(nval, 1.f);
    if (nval > 0.f) {
      lb += acc[l] / denom;
      lc += acc[3 + l] / (denom * (float)NCLS);
    }
    lo += acc[9 + l] / cnts[l];
  }
  lb *= 0.05f;
  lc *= 0.58f;   // lo *= 1.0
  out[0] = lb + lo + lc;
  out[1] = lb;
  out[2] = lo;
  out[3] = lc;
}

extern "C" void kernel_launch(void* const* d_in, const int* in_sizes, int n_in,
                              void* d_out, int out_size, void* d_ws, size_t ws_size,
                              hipStream_t stream) {
  const float* p0 = (const float*)d_in[0];
  const float* p1 = (const float*)d_in[1];
  const float* p2 = (const float*)d_in[2];
  const float* yt = (const float*)d_in[3];

  float*        wsf   = (float*)d_ws;
  unsigned int* gtobj = (unsigned int*)d_ws;
  float*        acc   = wsf + ACC_OFF;
  unsigned int* ncand = (unsigned int*)(wsf + NCAND_OFF);
  unsigned int* cand  = (unsigned int*)(wsf + CAND_OFF);

  hipMemsetAsync(d_ws, 0, ZERO_UNITS * sizeof(float), stream);
  k_compact<<<BB, 256, 0, stream>>>(yt, cand, ncand);
  k_gather<<<256, 512, 0, stream>>>(p0, p1, p2, yt, cand, ncand, gtobj, acc);
  k_obj<<<394, 256, 0, stream>>>(p0, p1, p2, gtobj, acc);
  k_fin<<<1, 1, 0, stream>>>(acc, (float*)d_out);
}